// Round 1
// baseline (1705.075 us; speedup 1.0000x reference)
//
#include <hip/hip_runtime.h>
#include <math.h>

#define N_ATOMS 200000
#define M_NBR 12
#define F_DIM 64
#define NBR_FEA 41
#define ORIG_F 92
#define B_CRYS 2000
#define APB 100
#define SH_DIM 9
#define NCONV 3
#define HFEA 128
#define EDGES (N_ATOMS * M_NBR)   // 2,400,000

// softplus(x) = log(1+exp(x)), stable form
__device__ __forceinline__ float softplus_f(float x) {
    return fmaxf(x, 0.0f) + __logf(1.0f + __expf(-fabsf(x)));
}

// x = atom_fea @ W_emb + b_emb  (200000x92 @ 92x64)
__global__ __launch_bounds__(256) void k_embed(
    const float* __restrict__ atom_fea, const float* __restrict__ W_emb,
    const float* __restrict__ b_emb, float* __restrict__ x)
{
    __shared__ float ldsW[ORIG_F * F_DIM];   // 92*64*4 = 23.5 KB
    __shared__ float ldsA[16 * ORIG_F];      // 16*92*4 = 5.9 KB
    int tid = threadIdx.x;
    for (int i = tid; i < ORIG_F * F_DIM; i += 256) ldsW[i] = W_emb[i];
    long base = (long)blockIdx.x * 16;
    for (int i = tid; i < 16 * ORIG_F; i += 256) ldsA[i] = atom_fea[base * ORIG_F + i];
    __syncthreads();
    int col = tid & 63;
    int rg  = tid >> 6;                       // 4 row-groups of 4 rows
    float a0 = 0.f, a1 = 0.f, a2 = 0.f, a3 = 0.f;
    const float* Ar = &ldsA[(rg * 4) * ORIG_F];
    for (int k = 0; k < ORIG_F; ++k) {
        float wv = ldsW[k * F_DIM + col];
        a0 = fmaf(Ar[0 * ORIG_F + k], wv, a0);
        a1 = fmaf(Ar[1 * ORIG_F + k], wv, a1);
        a2 = fmaf(Ar[2 * ORIG_F + k], wv, a2);
        a3 = fmaf(Ar[3 * ORIG_F + k], wv, a3);
    }
    float bb = b_emb[col];
    long o = (base + rg * 4) * F_DIM + col;
    x[o]             = a0 + bb;
    x[o + F_DIM]     = a1 + bb;
    x[o + 2 * F_DIM] = a2 + bb;
    x[o + 3 * F_DIM] = a3 + bb;
}

// Per edge, for all 3 layers: W0raw = softplus(e@Wr1[l]+br1[l]) . Wr2[l][:,0] + br2[l][0]
// One thread per edge; e row in VGPRs; weights via wave-uniform (scalar) loads.
__global__ __launch_bounds__(256) void k_filter(
    const float* __restrict__ nbr_fea, const float* __restrict__ Wr1,
    const float* __restrict__ br1, const float* __restrict__ Wr2,
    const float* __restrict__ br2, float* __restrict__ W0)
{
    __shared__ float ldsE[256 * NBR_FEA];    // 42 KB
    int tid = threadIdx.x;
    long ebase = (long)blockIdx.x * 256;
    for (int i = tid; i < 256 * NBR_FEA; i += 256)
        ldsE[i] = nbr_fea[ebase * NBR_FEA + i];
    __syncthreads();
    float e[NBR_FEA];
    #pragma unroll
    for (int k = 0; k < NBR_FEA; ++k) e[k] = ldsE[tid * NBR_FEA + k];

    for (int l = 0; l < NCONV; ++l) {
        const float* w1 = Wr1 + l * NBR_FEA * NBR_FEA;
        const float* b1 = br1 + l * NBR_FEA;
        const float* w2 = Wr2 + l * NBR_FEA * SH_DIM;
        float h[NBR_FEA];
        #pragma unroll
        for (int j = 0; j < NBR_FEA; ++j) h[j] = b1[j];
        for (int k = 0; k < NBR_FEA; ++k) {
            float ek = e[k];
            const float* wrow = w1 + k * NBR_FEA;
            #pragma unroll
            for (int j = 0; j < NBR_FEA; ++j) h[j] = fmaf(ek, wrow[j], h[j]);
        }
        float s = br2[l * SH_DIM];
        #pragma unroll
        for (int j = 0; j < NBR_FEA; ++j)
            s = fmaf(softplus_f(h[j]), w2[j * SH_DIM], s);
        W0[(long)l * EDGES + ebase + tid] = s;
    }
}

// Per atom: g = cscale * sum_j W0_j * x_in[src_j];  x_out = g @ Wtp[l]
// One wave per atom (lane = feature); 4 atoms per 256-thread block.
__global__ __launch_bounds__(256) void k_conv(
    const float* __restrict__ x_in, const int* __restrict__ nbr_idx,
    const float* __restrict__ W0, const float* __restrict__ Wtp,
    float* __restrict__ x_out)
{
    __shared__ float g[4][F_DIM];
    int tid  = threadIdx.x;
    int lane = tid & 63;
    int w    = tid >> 6;
    long atom = (long)blockIdx.x * 4 + w;
    const float cscale = 0.28209479177387814f * 0.125f / 12.0f;
    long eb = atom * M_NBR;
    float acc = 0.f;
    #pragma unroll
    for (int j = 0; j < M_NBR; ++j) {
        int idx  = nbr_idx[eb + j];
        float wj = W0[eb + j];
        acc = fmaf(wj, x_in[(long)idx * F_DIM + lane], acc);
    }
    g[w][lane] = acc * cscale;
    __syncthreads();
    float o = 0.f;
    #pragma unroll 8
    for (int f = 0; f < F_DIM; ++f)
        o = fmaf(g[w][f], Wtp[f * F_DIM + lane], o);
    x_out[atom * F_DIM + lane] = o;
}

// crys = mean over 100 atoms; h = softplus(crys@W_fc+b_fc); out = h@W_out+b_out
__global__ __launch_bounds__(128) void k_readout(
    const float* __restrict__ x, const int* __restrict__ cidx,
    const float* __restrict__ W_fc, const float* __restrict__ b_fc,
    const float* __restrict__ W_out, const float* __restrict__ b_out,
    float* __restrict__ out, float* __restrict__ hout)
{
    __shared__ float part[2][F_DIM];
    __shared__ float crys[F_DIM];
    __shared__ float hw[HFEA];
    int tid = threadIdx.x;
    int c = blockIdx.x;
    int f = tid & 63, half = tid >> 6;
    const int* ci = cidx + c * APB + half * (APB / 2);
    float p = 0.f;
    for (int a = 0; a < APB / 2; ++a)
        p += x[(long)ci[a] * F_DIM + f];
    part[half][f] = p;
    __syncthreads();
    if (tid < F_DIM) crys[tid] = (part[0][tid] + part[1][tid]) * (1.0f / APB);
    __syncthreads();
    float acc = b_fc[tid];
    for (int ff = 0; ff < F_DIM; ++ff)
        acc = fmaf(crys[ff], W_fc[ff * HFEA + tid], acc);
    float h = softplus_f(acc);
    hout[(long)c * HFEA + tid] = h;
    hw[tid] = h * W_out[tid];
    __syncthreads();
    if (tid == 0) {
        float s = b_out[0];
        #pragma unroll 16
        for (int j = 0; j < HFEA; ++j) s += hw[j];
        out[c] = s;
    }
}

extern "C" void kernel_launch(void* const* d_in, const int* in_sizes, int n_in,
                              void* d_out, int out_size, void* d_ws, size_t ws_size,
                              hipStream_t stream) {
    const float* atom_fea = (const float*)d_in[0];
    const float* nbr_fea  = (const float*)d_in[1];
    const int*   nbr_idx  = (const int*)d_in[2];
    const int*   cidx     = (const int*)d_in[3];
    // d_in[4] = pos : unused (Y[:, :1] is the constant l=0 channel)
    const float* W_emb = (const float*)d_in[5];
    const float* b_emb = (const float*)d_in[6];
    const float* Wr1   = (const float*)d_in[7];
    const float* br1   = (const float*)d_in[8];
    const float* Wr2   = (const float*)d_in[9];
    const float* br2   = (const float*)d_in[10];
    const float* Wtp   = (const float*)d_in[11];
    const float* W_fc  = (const float*)d_in[12];
    const float* b_fc  = (const float*)d_in[13];
    const float* W_out = (const float*)d_in[14];
    const float* b_out = (const float*)d_in[15];

    float* out  = (float*)d_out;       // 2000 (out) then 2000*128 (h)
    float* hout = out + B_CRYS;

    float* ws = (float*)d_ws;
    float* xA = ws;                                      // 200000*64
    float* xB = xA + (size_t)N_ATOMS * F_DIM;            // 200000*64
    float* W0 = xB + (size_t)N_ATOMS * F_DIM;            // 3*2400000

    k_embed <<<N_ATOMS / 16, 256, 0, stream>>>(atom_fea, W_emb, b_emb, xA);
    k_filter<<<EDGES / 256, 256, 0, stream>>>(nbr_fea, Wr1, br1, Wr2, br2, W0);
    k_conv  <<<N_ATOMS / 4, 256, 0, stream>>>(xA, nbr_idx, W0,             Wtp,                     xB);
    k_conv  <<<N_ATOMS / 4, 256, 0, stream>>>(xB, nbr_idx, W0 + EDGES,     Wtp + F_DIM * F_DIM,     xA);
    k_conv  <<<N_ATOMS / 4, 256, 0, stream>>>(xA, nbr_idx, W0 + 2 * EDGES, Wtp + 2 * F_DIM * F_DIM, xB);
    k_readout<<<B_CRYS, 128, 0, stream>>>(xB, cidx, W_fc, b_fc, W_out, b_out, out, hout);
}

// Round 2
// 1136.463 us; speedup vs baseline: 1.5003x; 1.5003x over previous
//
#include <hip/hip_runtime.h>
#include <hip/hip_bf16.h>
#include <math.h>

#define N_ATOMS 200000
#define M_NBR 12
#define F_DIM 64
#define NBR_FEA 41
#define ORIG_F 92
#define B_CRYS 2000
#define APB 100
#define SH_DIM 9
#define NCONV 3
#define HFEA 128
#define EDGES (N_ATOMS * M_NBR)   // 2,400,000

typedef __attribute__((ext_vector_type(8))) short short8;   // 8 bf16 = 4 VGPRs (MFMA A/B frag)
typedef __attribute__((ext_vector_type(4))) float floatx4;  // MFMA C/D frag

__device__ __forceinline__ float softplus_f(float x) {
    return fmaxf(x, 0.0f) + __logf(1.0f + __expf(-fabsf(x)));
}
__device__ __forceinline__ unsigned short f2bf(float f) {
    __hip_bfloat16 h = __float2bfloat16(f);   // RN
    return *reinterpret_cast<unsigned short*>(&h);
}
__device__ __forceinline__ float bf2f(unsigned int u) {
    unsigned int x = u << 16;
    union { unsigned int i; float f; } c; c.i = x; return c.f;
}

// ---------------------------------------------------------------------------
// x = atom_fea @ W_emb + b_emb  (200000x92 @ 92x64), output bf16
// ---------------------------------------------------------------------------
__global__ __launch_bounds__(256) void k_embed(
    const float* __restrict__ atom_fea, const float* __restrict__ W_emb,
    const float* __restrict__ b_emb, unsigned short* __restrict__ x)
{
    __shared__ float ldsW[ORIG_F * F_DIM];   // 23.5 KB
    __shared__ float ldsA[16 * ORIG_F];      // 5.9 KB
    int tid = threadIdx.x;
    for (int i = tid; i < ORIG_F * F_DIM; i += 256) ldsW[i] = W_emb[i];
    long base = (long)blockIdx.x * 16;
    for (int i = tid; i < 16 * ORIG_F; i += 256) ldsA[i] = atom_fea[base * ORIG_F + i];
    __syncthreads();
    int col = tid & 63;
    int rg  = tid >> 6;
    float a0 = 0.f, a1 = 0.f, a2 = 0.f, a3 = 0.f;
    const float* Ar = &ldsA[(rg * 4) * ORIG_F];
    for (int k = 0; k < ORIG_F; ++k) {
        float wv = ldsW[k * F_DIM + col];
        a0 = fmaf(Ar[0 * ORIG_F + k], wv, a0);
        a1 = fmaf(Ar[1 * ORIG_F + k], wv, a1);
        a2 = fmaf(Ar[2 * ORIG_F + k], wv, a2);
        a3 = fmaf(Ar[3 * ORIG_F + k], wv, a3);
    }
    float bb = b_emb[col];
    long o = (base + rg * 4) * F_DIM + col;
    x[o]             = f2bf(a0 + bb);
    x[o + F_DIM]     = f2bf(a1 + bb);
    x[o + 2 * F_DIM] = f2bf(a2 + bb);
    x[o + 3 * F_DIM] = f2bf(a3 + bb);
}

// ---------------------------------------------------------------------------
// Edge filter via bf16 MFMA.  Per 256-edge tile, all 3 layers:
//   W0[l][edge] = softplus(e @ Wr1[l] + br1[l]) . Wr2[l][:,0] + br2[l][0]
// E tile: 256x41 padded to 256x72 bf16 rows (144 B, 16B-aligned, 2-way-bank).
// Wt: W1 transposed n-major 48x72 bf16 (B-frag reads contiguous in K).
// ---------------------------------------------------------------------------
__global__ __launch_bounds__(256) void k_filter(
    const float* __restrict__ nbr_fea, const float* __restrict__ Wr1,
    const float* __restrict__ br1, const float* __restrict__ Wr2,
    const float* __restrict__ br2, float* __restrict__ W0)
{
    __shared__ __align__(16) unsigned short ldsA[256 * 72];  // 36864 B
    __shared__ __align__(16) unsigned short ldsWt[48 * 72];  // 6912 B
    __shared__ float ldsw2[48];
    __shared__ float ldsb1[48];

    int tid  = threadIdx.x;
    int lane = tid & 63;
    int wv   = tid >> 6;
    int sub  = lane & 15;      // m/n index within 16-tile
    int quad = lane >> 4;      // 0..3
    long ebase = (long)blockIdx.x * 256;

    // zero A tile (pad cols must be 0.0 bf16, and never stale NaN/Inf)
    {
        short8 z = {0,0,0,0,0,0,0,0};
        for (int i = tid * 8; i < 256 * 72; i += 256 * 8)
            *(short8*)&ldsA[i] = z;
    }
    __syncthreads();
    // stage E tile: 256x41 fp32 -> bf16, float4 global loads
    {
        const float4* src4 = (const float4*)(nbr_fea + ebase * NBR_FEA); // 2624 chunks
        for (int i = tid; i < 2624; i += 256) {
            float4 v = src4[i];
            int b = i * 4;
            int i0 = b,     r0 = i0 / 41, c0 = i0 - r0 * 41;
            int i1 = b + 1, r1 = i1 / 41, c1 = i1 - r1 * 41;
            int i2 = b + 2, r2 = i2 / 41, c2 = i2 - r2 * 41;
            int i3 = b + 3, r3 = i3 / 41, c3 = i3 - r3 * 41;
            ldsA[r0 * 72 + c0] = f2bf(v.x);
            ldsA[r1 * 72 + c1] = f2bf(v.y);
            ldsA[r2 * 72 + c2] = f2bf(v.z);
            ldsA[r3 * 72 + c3] = f2bf(v.w);
        }
    }

    for (int l = 0; l < NCONV; ++l) {
        __syncthreads();   // A staged (l=0) / prior layer's Wt reads done (l>0)
        // stage Wt (transposed, zero-padded), w2 col 0, b1
        for (int i = tid; i < 48 * 72; i += 256) {
            int n = i / 72, k = i - n * 72;
            unsigned short val = 0;
            if (n < NBR_FEA && k < NBR_FEA)
                val = f2bf(Wr1[l * NBR_FEA * NBR_FEA + k * NBR_FEA + n]);
            ldsWt[i] = val;
        }
        if (tid < 48) {
            ldsw2[tid] = (tid < NBR_FEA) ? Wr2[(l * NBR_FEA + tid) * SH_DIM] : 0.f;
            ldsb1[tid] = (tid < NBR_FEA) ? br1[l * NBR_FEA + tid] : 0.f;
        }
        __syncthreads();

        // MFMA: H(64x48 per wave) = E(64x64) @ W1(64x48)
        floatx4 acc[4][3];
        #pragma unroll
        for (int mt = 0; mt < 4; ++mt)
            #pragma unroll
            for (int nt = 0; nt < 3; ++nt)
                acc[mt][nt] = (floatx4){0.f, 0.f, 0.f, 0.f};

        #pragma unroll
        for (int s = 0; s < 2; ++s) {
            int koff = s * 32 + quad * 8;
            short8 bfr[3];
            #pragma unroll
            for (int nt = 0; nt < 3; ++nt)
                bfr[nt] = *(const short8*)&ldsWt[(nt * 16 + sub) * 72 + koff];
            #pragma unroll
            for (int mt = 0; mt < 4; ++mt) {
                short8 afr = *(const short8*)&ldsA[(wv * 64 + mt * 16 + sub) * 72 + koff];
                #pragma unroll
                for (int nt = 0; nt < 3; ++nt)
                    acc[mt][nt] = __builtin_amdgcn_mfma_f32_16x16x32_bf16(
                        afr, bfr[nt], acc[mt][nt], 0, 0, 0);
            }
        }

        // epilogue: s = sum_j softplus(H[m][j]+b1[j]) * w2[j] + br2[l][0]
        float w2v[3], b1v[3];
        #pragma unroll
        for (int nt = 0; nt < 3; ++nt) {
            w2v[nt] = ldsw2[nt * 16 + sub];
            b1v[nt] = ldsb1[nt * 16 + sub];
        }
        float r2b = br2[l * SH_DIM];
        #pragma unroll
        for (int mt = 0; mt < 4; ++mt) {
            float p[4];
            #pragma unroll
            for (int reg = 0; reg < 4; ++reg) {
                float t = 0.f;
                #pragma unroll
                for (int nt = 0; nt < 3; ++nt)
                    t += softplus_f(acc[mt][nt][reg] + b1v[nt]) * w2v[nt];
                t += __shfl_xor(t, 1);
                t += __shfl_xor(t, 2);
                t += __shfl_xor(t, 4);
                t += __shfl_xor(t, 8);
                p[reg] = t + r2b;
            }
            if (sub == 0) {
                long base = (long)l * EDGES + ebase + wv * 64 + mt * 16 + quad * 4;
                W0[base + 0] = p[0];
                W0[base + 1] = p[1];
                W0[base + 2] = p[2];
                W0[base + 3] = p[3];
            }
        }
    }
}

// ---------------------------------------------------------------------------
// Conv: g = cscale * sum_j W0_j * x_in[src_j];  x_out = g @ Wtp[l]
// x in bf16. Gather: 4 atoms/wave, lane = (atom<<4)|featquad, dwordx2 loads.
// ---------------------------------------------------------------------------
__global__ __launch_bounds__(256) void k_conv(
    const unsigned short* __restrict__ x_in, const int* __restrict__ nbr_idx,
    const float* __restrict__ W0, const float* __restrict__ Wtp,
    unsigned short* __restrict__ x_out)
{
    __shared__ float g[16][F_DIM];   // 4 KB
    int tid  = threadIdx.x;
    int lane = tid & 63;
    int wv   = tid >> 6;
    int aw   = lane >> 4;            // atom within wave 0..3
    int fq   = lane & 15;            // features 4fq..4fq+3
    const float cscale = 0.28209479177387814f * 0.125f / 12.0f;

    long atom = (long)blockIdx.x * 16 + wv * 4 + aw;
    long eb = atom * M_NBR;
    float4 acc = {0.f, 0.f, 0.f, 0.f};
    #pragma unroll
    for (int j = 0; j < M_NBR; ++j) {
        int   idx = nbr_idx[eb + j];     // broadcast within 16-lane group
        float wj  = W0[eb + j];
        uint2 v = *(const uint2*)(x_in + (size_t)idx * F_DIM + fq * 4);
        acc.x = fmaf(wj, bf2f(v.x & 0xffffu), acc.x);
        acc.y = fmaf(wj, bf2f(v.x >> 16),     acc.y);
        acc.z = fmaf(wj, bf2f(v.y & 0xffffu), acc.z);
        acc.w = fmaf(wj, bf2f(v.y >> 16),     acc.w);
    }
    float4 gv = {acc.x * cscale, acc.y * cscale, acc.z * cscale, acc.w * cscale};
    *(float4*)&g[wv * 4 + aw][fq * 4] = gv;
    __syncthreads();

    // TP: wave wv -> atoms wv*4..+3, lane = output feature
    int f = lane;
    float o0 = 0.f, o1 = 0.f, o2 = 0.f, o3 = 0.f;
    int r0 = wv * 4;
    for (int k4 = 0; k4 < F_DIM; k4 += 4) {
        float4 ga = *(const float4*)&g[r0 + 0][k4];
        float4 gb = *(const float4*)&g[r0 + 1][k4];
        float4 gc = *(const float4*)&g[r0 + 2][k4];
        float4 gd = *(const float4*)&g[r0 + 3][k4];
        #pragma unroll
        for (int t = 0; t < 4; ++t) {
            float wtv = Wtp[(k4 + t) * F_DIM + f];
            float gaa = (t == 0) ? ga.x : (t == 1) ? ga.y : (t == 2) ? ga.z : ga.w;
            float gbb = (t == 0) ? gb.x : (t == 1) ? gb.y : (t == 2) ? gb.z : gb.w;
            float gcc = (t == 0) ? gc.x : (t == 1) ? gc.y : (t == 2) ? gc.z : gc.w;
            float gdd = (t == 0) ? gd.x : (t == 1) ? gd.y : (t == 2) ? gd.z : gd.w;
            o0 = fmaf(gaa, wtv, o0);
            o1 = fmaf(gbb, wtv, o1);
            o2 = fmaf(gcc, wtv, o2);
            o3 = fmaf(gdd, wtv, o3);
        }
    }
    size_t ob = ((size_t)blockIdx.x * 16 + r0) * F_DIM + f;
    x_out[ob]             = f2bf(o0);
    x_out[ob + F_DIM]     = f2bf(o1);
    x_out[ob + 2 * F_DIM] = f2bf(o2);
    x_out[ob + 3 * F_DIM] = f2bf(o3);
}

// ---------------------------------------------------------------------------
// Readout
// ---------------------------------------------------------------------------
__global__ __launch_bounds__(128) void k_readout(
    const unsigned short* __restrict__ x, const int* __restrict__ cidx,
    const float* __restrict__ W_fc, const float* __restrict__ b_fc,
    const float* __restrict__ W_out, const float* __restrict__ b_out,
    float* __restrict__ out, float* __restrict__ hout)
{
    __shared__ float part[2][F_DIM];
    __shared__ float crys[F_DIM];
    __shared__ float hw[HFEA];
    int tid = threadIdx.x;
    int c = blockIdx.x;
    int f = tid & 63, half = tid >> 6;
    const int* ci = cidx + c * APB + half * (APB / 2);
    float p = 0.f;
    for (int a = 0; a < APB / 2; ++a)
        p += bf2f(x[(size_t)ci[a] * F_DIM + f]);
    part[half][f] = p;
    __syncthreads();
    if (tid < F_DIM) crys[tid] = (part[0][tid] + part[1][tid]) * (1.0f / APB);
    __syncthreads();
    float acc = b_fc[tid];
    for (int ff = 0; ff < F_DIM; ++ff)
        acc = fmaf(crys[ff], W_fc[ff * HFEA + tid], acc);
    float h = softplus_f(acc);
    hout[(size_t)c * HFEA + tid] = h;
    hw[tid] = h * W_out[tid];
    __syncthreads();
    if (tid == 0) {
        float s = b_out[0];
        #pragma unroll 16
        for (int j = 0; j < HFEA; ++j) s += hw[j];
        out[c] = s;
    }
}

extern "C" void kernel_launch(void* const* d_in, const int* in_sizes, int n_in,
                              void* d_out, int out_size, void* d_ws, size_t ws_size,
                              hipStream_t stream) {
    const float* atom_fea = (const float*)d_in[0];
    const float* nbr_fea  = (const float*)d_in[1];
    const int*   nbr_idx  = (const int*)d_in[2];
    const int*   cidx     = (const int*)d_in[3];
    // d_in[4] = pos : unused (Y[:, :1] is the constant l=0 channel)
    const float* W_emb = (const float*)d_in[5];
    const float* b_emb = (const float*)d_in[6];
    const float* Wr1   = (const float*)d_in[7];
    const float* br1   = (const float*)d_in[8];
    const float* Wr2   = (const float*)d_in[9];
    const float* br2   = (const float*)d_in[10];
    const float* Wtp   = (const float*)d_in[11];
    const float* W_fc  = (const float*)d_in[12];
    const float* b_fc  = (const float*)d_in[13];
    const float* W_out = (const float*)d_in[14];
    const float* b_out = (const float*)d_in[15];

    float* out  = (float*)d_out;
    float* hout = out + B_CRYS;

    float* W0 = (float*)d_ws;                                   // 3*2.4M fp32
    unsigned short* xA = (unsigned short*)(W0 + 3 * (size_t)EDGES);
    unsigned short* xB = xA + (size_t)N_ATOMS * F_DIM;

    k_embed <<<N_ATOMS / 16, 256, 0, stream>>>(atom_fea, W_emb, b_emb, xA);
    k_filter<<<EDGES / 256, 256, 0, stream>>>(nbr_fea, Wr1, br1, Wr2, br2, W0);
    k_conv  <<<N_ATOMS / 16, 256, 0, stream>>>(xA, nbr_idx, W0,             Wtp,                     xB);
    k_conv  <<<N_ATOMS / 16, 256, 0, stream>>>(xB, nbr_idx, W0 + EDGES,     Wtp + F_DIM * F_DIM,     xA);
    k_conv  <<<N_ATOMS / 16, 256, 0, stream>>>(xA, nbr_idx, W0 + 2 * EDGES, Wtp + 2 * F_DIM * F_DIM, xB);
    k_readout<<<B_CRYS, 128, 0, stream>>>(xB, cidx, W_fc, b_fc, W_out, b_out, out, hout);
}